// Round 2
// baseline (1121.963 us; speedup 1.0000x reference)
//
#include <hip/hip_runtime.h>

typedef _Float16 half8 __attribute__((ext_vector_type(8)));
typedef float floatx4 __attribute__((ext_vector_type(4)));

#define MFMA16(a, b, c) __builtin_amdgcn_mfma_f32_16x16x32_f16((a), (b), (c), 0, 0, 0)

// ws layout (units: _Float16 elements)
#define OFF_W1 0        // [mat2][nt6][ks24][lane64][8]  -> 147456 halves
#define OFF_W2 147456   // [mat2][nt3][ks3][64][8]       -> 9216
#define OFF_W3 156672   // [mat2][nt2][ks2][64][8]       -> 4096
#define OFF_W4 160768   // [mat2][64][8]                 -> 1024
#define OFF_W5 161792   // [mat2][64][8]                 -> 1024

// ---------------------------------------------------------------------------
// Prep: fp32 weights [N x K] -> fp16 MFMA B-fragment layout, zero-padded.
// (unchanged from the verified kernel)
// ---------------------------------------------------------------------------
__global__ __launch_bounds__(64) void prep_weights(
    const float* __restrict__ eW1, const float* __restrict__ sW1,
    const float* __restrict__ eW2, const float* __restrict__ sW2,
    const float* __restrict__ eW3, const float* __restrict__ sW3,
    const float* __restrict__ eW4, const float* __restrict__ sW4,
    const float* __restrict__ eW5, const float* __restrict__ sW5,
    _Float16* __restrict__ ws)
{
    int b = blockIdx.x;
    int lane = threadIdx.x;
    const float* src;
    _Float16* dst;
    int N, K, nt, ks;
    if (b < 288) {
        int mat = b / 144, r = b % 144;
        nt = r / 24; ks = r % 24;
        src = mat ? sW1 : eW1; N = 96; K = 768;
        dst = ws + OFF_W1 + (size_t)((mat * 6 + nt) * 24 + ks) * 512;
    } else if (b < 306) {
        int i = b - 288, mat = i / 9, r = i % 9;
        nt = r / 3; ks = r % 3;
        src = mat ? sW2 : eW2; N = 48; K = 96;
        dst = ws + OFF_W2 + (size_t)((mat * 3 + nt) * 3 + ks) * 512;
    } else if (b < 314) {
        int i = b - 306, mat = i / 4, r = i % 4;
        nt = r / 2; ks = r % 2;
        src = mat ? sW3 : eW3; N = 24; K = 48;
        dst = ws + OFF_W3 + (size_t)((mat * 2 + nt) * 2 + ks) * 512;
    } else if (b < 316) {
        int mat = b - 314;
        nt = 0; ks = 0;
        src = mat ? sW4 : eW4; N = 12; K = 24;
        dst = ws + OFF_W4 + (size_t)mat * 512;
    } else {
        int mat = b - 316;
        nt = 0; ks = 0;
        src = mat ? sW5 : eW5; N = mat ? 2 : 8; K = 12;
        dst = ws + OFF_W5 + (size_t)mat * 512;
    }
    int n = nt * 16 + (lane & 15);
    int kb = ks * 32 + (lane >> 4) * 8;
    for (int j = 0; j < 8; ++j) {
        int k = kb + j;
        float v = (n < N && k < K) ? src[n * K + k] : 0.0f;
        dst[lane * 8 + j] = (_Float16)v;
    }
}

// fp32 pair -> packed 2x fp16 (RTE via _Float16 cast), low half = first arg
__device__ __forceinline__ unsigned int packh(float a, float b) {
    union { _Float16 h[2]; unsigned int u; } x;
    x.h[0] = (_Float16)a;
    x.h[1] = (_Float16)b;
    return x.u;
}

// ---------------------------------------------------------------------------
// Fused net. Block = 256 threads = 4 waves, 32 samples.
// Wave w: mat = w>>1 (0=e,1=s), mh = w&1 (0=pair pooling, 1=seq pooling).
//
// Phase 1 (layer-1, K=768) is REGISTER-DIRECT: no LDS staging, no
// global_load_lds, no per-chunk __syncthreads (the old structure drained
// vmcnt(0) 24x per block -> ~10-25% HBM util). Each wave loads its chunk
// coalesced (lane -> (sample=lane>>3, kquad=lane&7): 8x128B segments/instr),
// pools+relus+packs fp16 in registers, then transposes sample<->k with
// 8 __shfl + selects into the exact 16x16x32 A-fragment. e/s/pair/seq
// waves re-read the same lines; L1/L2 absorb the ~3x reuse, HBM sees the
// input once (~0.8 GB).
//
// LDS: only the epilogue buffers. Y1 (stride 104) needs 128*104*2 = 26624 B;
// Y2 (72) / Y3,Y4 (40) reuse in place; Eo/So at 26624. Total 29184 B.
// __launch_bounds__(256,3): 12 waves/CU — ample TLP for a BW-bound loop with
// 8-16 independent loads in flight per wave.
// ---------------------------------------------------------------------------
__global__ __launch_bounds__(256, 3) void fused_net(
    const float* __restrict__ result,
    const float* __restrict__ e_pair, const float* __restrict__ s_pair,
    const float* __restrict__ e_seq,  const float* __restrict__ s_seq,
    const float* __restrict__ cross_w,
    const _Float16* __restrict__ ws,
    float* __restrict__ out)
{
    __shared__ __align__(16) unsigned char lds_raw[29184];
    float* EoLDS = (float*)(lds_raw + 26624);         // [64][8]
    float* SoLDS = (float*)(lds_raw + 26624 + 2048);  // [64][2]

    const int tid  = threadIdx.x;
    const int lane = tid & 63;
    const int wave = tid >> 6;
    const int l15  = lane & 15;
    const int q    = lane >> 4;
    const int mat  = wave >> 1;   // 0 = e, 1 = s
    const int mh   = wave & 1;    // 0 = pair, 1 = seq
    const int sbase = blockIdx.x * 32;

    // wave-uniform pooling coefficients
    float w0, w1, w2 = 0.f, w3 = 0.f;
    if (mh == 0) {
        w0 = mat ? s_pair[0] : e_pair[0];
        w1 = mat ? s_pair[1] : e_pair[1];
    } else {
        w0 = mat ? s_seq[0] : e_seq[0];
        w1 = mat ? s_seq[1] : e_seq[1];
        w2 = mat ? s_seq[2] : e_seq[2];
        w3 = mat ? s_seq[3] : e_seq[3];
    }

    const floatx4 zf4 = {0.f, 0.f, 0.f, 0.f};

    // ---------------- Phase 1: layer-1 GEMM, register-direct ---------------
    floatx4 acc[2][6];
#pragma unroll
    for (int m = 0; m < 2; ++m)
#pragma unroll
        for (int n = 0; n < 6; ++n) acc[m][n] = zf4;

    const half8* Bw1 = (const half8*)(ws + OFF_W1) + (size_t)mat * (6 * 24 * 64);

    // load-lane mapping: this lane loads sample (ls + 8/16/24), k-quad lj4
    const int ls  = lane >> 3;   // 0..7
    const int lj4 = lane & 7;    // 0..7 (float4 within 32-float chunk)
    const float* rb0 = result + (size_t)(sbase + ls) * 3072 + lj4 * 4;

    // shuffle-transpose: dest lane (row=l15, q) pulls quad 2q / 2q+1 of
    // sample l15 from load lane ((l15&7)*8 + 2q(+1)), register-half = l15>>3
    const int src0 = ((l15 & 7) << 3) | (q << 1);
    const int src1 = src0 + 1;
    const bool hiHalf = (l15 >> 3) != 0;

    for (int kc = 0; kc < 24; ++kc) {
        half8 afrag[2];
        const float* rk = rb0 + kc * 32;
#pragma unroll
        for (int gg = 0; gg < 2; ++gg) {
            const float* g0 = rk + (size_t)gg * 16 * 3072;   // sample ls+16gg
            const float* g1 = g0 + 8 * 3072;                 // sample ls+16gg+8
            floatx4 pA, pB;
            if (mh == 0) {
                floatx4 a0 = *(const floatx4*)(g0);
                floatx4 c0 = *(const floatx4*)(g0 + 2 * 768);
                floatx4 a1 = *(const floatx4*)(g1);
                floatx4 c1 = *(const floatx4*)(g1 + 2 * 768);
                pA = w0 * a0 + w1 * c0;
                pB = w0 * a1 + w1 * c1;
            } else {
                floatx4 a0 = *(const floatx4*)(g0);
                floatx4 b0 = *(const floatx4*)(g0 + 768);
                floatx4 c0 = *(const floatx4*)(g0 + 2 * 768);
                floatx4 d0 = *(const floatx4*)(g0 + 3 * 768);
                floatx4 a1 = *(const floatx4*)(g1);
                floatx4 b1 = *(const floatx4*)(g1 + 768);
                floatx4 c1 = *(const floatx4*)(g1 + 2 * 768);
                floatx4 d1 = *(const floatx4*)(g1 + 3 * 768);
                pA = w0 * a0 + w1 * b0 + w2 * c0 + w3 * d0;
                pB = w0 * a1 + w1 * b1 + w2 * c1 + w3 * d1;
            }
            // relu + fp16 pack: uL* = low-half sample, uH* = +8 sample
            unsigned int uL0 = packh(fmaxf(pA[0], 0.f), fmaxf(pA[1], 0.f));
            unsigned int uL1 = packh(fmaxf(pA[2], 0.f), fmaxf(pA[3], 0.f));
            unsigned int uH0 = packh(fmaxf(pB[0], 0.f), fmaxf(pB[1], 0.f));
            unsigned int uH1 = packh(fmaxf(pB[2], 0.f), fmaxf(pB[3], 0.f));
            // transpose to A-fragment lanes
            unsigned int w0L = (unsigned int)__shfl((int)uL0, src0);
            unsigned int w0H = (unsigned int)__shfl((int)uH0, src0);
            unsigned int w1L = (unsigned int)__shfl((int)uL1, src0);
            unsigned int w1H = (unsigned int)__shfl((int)uH1, src0);
            unsigned int w2L = (unsigned int)__shfl((int)uL0, src1);
            unsigned int w2H = (unsigned int)__shfl((int)uH0, src1);
            unsigned int w3L = (unsigned int)__shfl((int)uL1, src1);
            unsigned int w3H = (unsigned int)__shfl((int)uH1, src1);
            union { unsigned int u[4]; half8 h; } f;
            f.u[0] = hiHalf ? w0H : w0L;   // k = 8q+0,1
            f.u[1] = hiHalf ? w1H : w1L;   // k = 8q+2,3
            f.u[2] = hiHalf ? w2H : w2L;   // k = 8q+4,5
            f.u[3] = hiHalf ? w3H : w3L;   // k = 8q+6,7
            afrag[gg] = f.h;
        }
#pragma unroll
        for (int nt = 0; nt < 6; ++nt) {
            half8 bf = Bw1[(nt * 24 + kc) * 64 + lane];
            acc[0][nt] = MFMA16(afrag[0], bf, acc[0][nt]);
            acc[1][nt] = MFMA16(afrag[1], bf, acc[1][nt]);
        }
    }

    _Float16* Y = (_Float16*)lds_raw;

    // ---------------- Phase 2: Y1 = relu(L1) fp16, stride 104 ---------------
#pragma unroll
    for (int m = 0; m < 2; ++m)
#pragma unroll
        for (int nt = 0; nt < 6; ++nt)
#pragma unroll
            for (int r = 0; r < 4; ++r) {
                int row = mat * 64 + mh * 32 + m * 16 + q * 4 + r;
                Y[row * 104 + nt * 16 + l15] = (_Float16)fmaxf(acc[m][nt][r], 0.f);
            }
    __syncthreads();

    // ---------------- Phase 3: layer-2 (96 -> 48) ---------------------------
    floatx4 acc2[2][3];
#pragma unroll
    for (int m = 0; m < 2; ++m)
#pragma unroll
        for (int n = 0; n < 3; ++n) acc2[m][n] = zf4;
    {
        const _Float16* A2 = Y + mat * 64 * 104;
        const half8* Bw2 = (const half8*)(ws + OFF_W2) + (size_t)mat * (3 * 3 * 64);
#pragma unroll
        for (int ks2 = 0; ks2 < 3; ++ks2) {
            half8 a0 = *(const half8*)(A2 + (mh * 32 + l15) * 104 + ks2 * 32 + q * 8);
            half8 a1 = *(const half8*)(A2 + (mh * 32 + 16 + l15) * 104 + ks2 * 32 + q * 8);
#pragma unroll
            for (int nt = 0; nt < 3; ++nt) {
                half8 bf = Bw2[(nt * 3 + ks2) * 64 + lane];
                acc2[0][nt] = MFMA16(a0, bf, acc2[0][nt]);
                acc2[1][nt] = MFMA16(a1, bf, acc2[1][nt]);
            }
        }
    }
    __syncthreads();   // all Y1 reads done before overwrite
    // write Y2 stride 72, zero-pad cols 48..63
#pragma unroll
    for (int m = 0; m < 2; ++m)
#pragma unroll
        for (int nt = 0; nt < 3; ++nt)
#pragma unroll
            for (int r = 0; r < 4; ++r) {
                int row = mat * 64 + mh * 32 + m * 16 + q * 4 + r;
                Y[row * 72 + nt * 16 + l15] = (_Float16)fmaxf(acc2[m][nt][r], 0.f);
            }
    for (int i = tid; i < 2048; i += 256) {
        int row = i >> 4;
        Y[row * 72 + 48 + (i & 15)] = (_Float16)0.f;
    }
    __syncthreads();

    // ---------------- Phase 4: layer-3 (48 -> 24), K padded to 64 -----------
    floatx4 acc3[2][2];
#pragma unroll
    for (int m = 0; m < 2; ++m)
#pragma unroll
        for (int n = 0; n < 2; ++n) acc3[m][n] = zf4;
    {
        const _Float16* A3 = Y + mat * 64 * 72;
        const half8* Bw3 = (const half8*)(ws + OFF_W3) + (size_t)mat * (2 * 2 * 64);
#pragma unroll
        for (int ks2 = 0; ks2 < 2; ++ks2) {
            half8 a0 = *(const half8*)(A3 + (mh * 32 + l15) * 72 + ks2 * 32 + q * 8);
            half8 a1 = *(const half8*)(A3 + (mh * 32 + 16 + l15) * 72 + ks2 * 32 + q * 8);
#pragma unroll
            for (int nt = 0; nt < 2; ++nt) {
                half8 bf = Bw3[(nt * 2 + ks2) * 64 + lane];
                acc3[0][nt] = MFMA16(a0, bf, acc3[0][nt]);
                acc3[1][nt] = MFMA16(a1, bf, acc3[1][nt]);
            }
        }
    }
    __syncthreads();
    // write Y3 stride 40, zero-pad cols 24..31
#pragma unroll
    for (int m = 0; m < 2; ++m)
#pragma unroll
        for (int nt = 0; nt < 2; ++nt)
#pragma unroll
            for (int r = 0; r < 4; ++r) {
                int row = mat * 64 + mh * 32 + m * 16 + q * 4 + r;
                Y[row * 40 + nt * 16 + l15] = (_Float16)fmaxf(acc3[m][nt][r], 0.f);
            }
    for (int i = tid; i < 1024; i += 256) {
        int row = i >> 3;
        Y[row * 40 + 24 + (i & 7)] = (_Float16)0.f;
    }
    __syncthreads();

    // ---------------- Phase 5: layer-4 (24 -> 12), K padded to 32 -----------
    floatx4 acc4[2];
    {
        const _Float16* A4 = Y + mat * 64 * 40;
        const half8* Bw4 = (const half8*)(ws + OFF_W4) + (size_t)mat * 64;
        half8 a0 = *(const half8*)(A4 + (mh * 32 + l15) * 40 + q * 8);
        half8 a1 = *(const half8*)(A4 + (mh * 32 + 16 + l15) * 40 + q * 8);
        half8 bf = Bw4[lane];
        acc4[0] = MFMA16(a0, bf, zf4);
        acc4[1] = MFMA16(a1, bf, zf4);
    }
    __syncthreads();
    // write Y4 stride 40, zero-pad cols 12..31
#pragma unroll
    for (int m = 0; m < 2; ++m)
#pragma unroll
        for (int r = 0; r < 4; ++r) {
            int row = mat * 64 + mh * 32 + m * 16 + q * 4 + r;
            Y[row * 40 + l15] = (_Float16)fmaxf(acc4[m][r], 0.f);
        }
    for (int i = tid; i < 2560; i += 256) {
        int row = i / 20;
        Y[row * 40 + 12 + (i % 20)] = (_Float16)0.f;
    }
    __syncthreads();

    // ---------------- Phase 6: layer-5 (12 -> 8 or 2), K padded to 32 -------
    floatx4 acc5[2];
    {
        const _Float16* A5 = Y + mat * 64 * 40;
        const half8* Bw5 = (const half8*)(ws + OFF_W5) + (size_t)mat * 64;
        half8 a0 = *(const half8*)(A5 + (mh * 32 + l15) * 40 + q * 8);
        half8 a1 = *(const half8*)(A5 + (mh * 32 + 16 + l15) * 40 + q * 8);
        half8 bf = Bw5[lane];
        acc5[0] = MFMA16(a0, bf, zf4);
        acc5[1] = MFMA16(a1, bf, zf4);
    }
    if (mat == 0) {
        if (l15 < 8) {
#pragma unroll
            for (int m = 0; m < 2; ++m)
#pragma unroll
                for (int r = 0; r < 4; ++r) {
                    int row = mh * 32 + m * 16 + q * 4 + r;  // 0..31 pair, 32..63 seq
                    EoLDS[row * 8 + l15] = acc5[m][r];
                }
        }
    } else {
        if (l15 < 2) {
#pragma unroll
            for (int m = 0; m < 2; ++m)
#pragma unroll
                for (int r = 0; r < 4; ++r) {
                    int row = mh * 32 + m * 16 + q * 4 + r;
                    SoLDS[row * 2 + l15] = acc5[m][r];
                }
        }
    }
    __syncthreads();

    // ---------------- Phase 7: cross-mul + combine --------------------------
    if (tid < 64) {
        int sample = tid >> 1;
        int h = tid & 1;
        float cw0 = cross_w[0], cw1 = cross_w[1];
        float pes = 0.f, ses = 0.f;
#pragma unroll
        for (int j = 0; j < 8; ++j) {
            pes += EoLDS[sample * 8 + j];
            ses += EoLDS[(32 + sample) * 8 + j];
        }
        float v = cw0 * SoLDS[sample * 2 + h] * pes
                + cw1 * SoLDS[(32 + sample) * 2 + h] * ses;
        out[(size_t)(sbase + sample) * 2 + h] = v;
    }
}

extern "C" void kernel_launch(void* const* d_in, const int* in_sizes, int n_in,
                              void* d_out, int out_size, void* d_ws, size_t ws_size,
                              hipStream_t stream) {
    (void)n_in; (void)out_size; (void)ws_size;
    const float* result = (const float*)d_in[0];
    const float* sW1 = (const float*)d_in[1];
    const float* sW2 = (const float*)d_in[2];
    const float* sW3 = (const float*)d_in[3];
    const float* sW4 = (const float*)d_in[4];
    const float* sW5 = (const float*)d_in[5];
    const float* eW1 = (const float*)d_in[6];
    const float* eW2 = (const float*)d_in[7];
    const float* eW3 = (const float*)d_in[8];
    const float* eW4 = (const float*)d_in[9];
    const float* eW5 = (const float*)d_in[10];
    const float* s_seq  = (const float*)d_in[11];
    const float* s_pair = (const float*)d_in[12];
    const float* e_seq  = (const float*)d_in[13];
    const float* e_pair = (const float*)d_in[14];
    const float* cross_w = (const float*)d_in[15];
    _Float16* ws = (_Float16*)d_ws;
    float* out = (float*)d_out;

    int B = in_sizes[0] / 3072;   // 65536

    prep_weights<<<dim3(318), dim3(64), 0, stream>>>(
        eW1, sW1, eW2, sW2, eW3, sW3, eW4, sW4, eW5, sW5, ws);

    fused_net<<<dim3(B / 32), dim3(256), 0, stream>>>(
        result, e_pair, s_pair, e_seq, s_seq, cross_w, ws, out);
}